// Round 9
// baseline (372.231 us; speedup 1.0000x reference)
//
#include <hip/hip_runtime.h>
#include <hip/hip_bf16.h>
#include <stdint.h>

// GraphSAGE 2-layer encoder — bucketed CSR build + MFMA GEMM layers.
// R9: split-K weight staging (two 16KB halves, one shared buffer) halves LDS
// -> 4 blocks/CU, __launch_bounds__(512,8) for 32 waves/CU potential.

typedef unsigned short u16;
typedef __attribute__((ext_vector_type(8))) short short8;   // bf16x8 A/B frag
typedef __attribute__((ext_vector_type(4))) float f32x4;    // fp32x4 C/D frag

#define BSHIFT 9
#define BSIZE  512          // nodes per bucket
#define CHUNK  8192         // edges per partition block

__device__ __forceinline__ float bf2f(u16 v) { return __uint_as_float(((uint32_t)v) << 16); }
__device__ __forceinline__ float bfu_lo(uint32_t u) { return __uint_as_float(u << 16); }
__device__ __forceinline__ float bfu_hi(uint32_t u) { return __uint_as_float(u & 0xffff0000u); }
__device__ __forceinline__ u16 f2bf(float f) {
    uint32_t u = __float_as_uint(f);
    return (u16)((u + 0x7fffu + ((u >> 16) & 1u)) >> 16);
}

// ---------------- probe: dtype flags ----------------
__global__ __launch_bounds__(256) void probe_k(
    const void* x, const void* w1l, const void* w1r, const void* b1,
    const void* w2l, const void* w2r, const void* b2, const void* ei,
    int* __restrict__ flags, int ne,
    int c0, int c1, int c2, int c3, int c4, int c5, int c6) {
    __shared__ int cs_s[8];
    int tid = threadIdx.x, a = tid >> 5, lane = tid & 31;
    if (tid < 8) cs_s[tid] = 0;
    __syncthreads();
    if (a < 7) {
        const void* ptrs[7] = {x, w1l, w1r, b1, w2l, w2r, b2};
        int cs[7] = {c0, c1, c2, c3, c4, c5, c6};
        int C = cs[a];
        int stride = C / 32; if (stride < 1) stride = 1;
        long long i = (long long)lane * stride;
        if (i > C - 1) i = C - 1;
        i &= ~1LL;
        u16 v = ((const u16*)ptrs[a])[i];
        int e = (v >> 7) & 0xFF;
        int sane = ((e >= 0x50 && e <= 0x97) || v == 0) ? 1 : 0;
        atomicAdd(&cs_s[a], sane);
    } else {
        long long n32 = 2LL * ne;
        long long stride = n32 / 32; if (stride < 1) stride = 1;
        long long i = (long long)lane * stride; i |= 1;
        if (i >= n32) i = 1;
        int wv = ((const int*)ei)[i];
        atomicAdd(&cs_s[7], wv != 0 ? 1 : 0);
    }
    __syncthreads();
    if (tid < 7) flags[tid] = (cs_s[tid] >= 24) ? 1 : 0;
    if (tid == 7) flags[7] = (cs_s[7] == 0) ? 1 : 0;
}

// ---------------- bucket histogram ----------------
__global__ __launch_bounds__(256) void bucket_count(
    const void* __restrict__ ei, int* __restrict__ bcnt,
    const int* __restrict__ flags, int nn, int ne, int nb) {
    __shared__ int hist[512];
    for (int i = threadIdx.x; i < 512; i += 256) hist[i] = 0;
    __syncthreads();
    int e64 = flags[7];
    int stride = gridDim.x * 256;
    for (int e = blockIdx.x * 256 + threadIdx.x; e < ne; e += stride) {
        int dst = e64 ? (int)((const long long*)ei)[(size_t)ne + e]
                      : ((const int*)ei)[(size_t)ne + e];
        if ((unsigned)dst < (unsigned)nn) atomicAdd(&hist[dst >> BSHIFT], 1);
    }
    __syncthreads();
    for (int i = threadIdx.x; i < nb; i += 256)
        if (hist[i]) atomicAdd(&bcnt[i], hist[i]);
}

// ---------------- bucket scan (parallel) ----------------
__global__ __launch_bounds__(512) void scan_buckets(
    const int* __restrict__ bcnt, int* __restrict__ bo,
    int* __restrict__ bcur, int nb) {
    __shared__ int t0[512];
    int tid = threadIdx.x;
    int v = (tid < nb) ? bcnt[tid] : 0;
    t0[tid] = v;
    __syncthreads();
    for (int d = 1; d < 512; d <<= 1) {
        int t = (tid >= d) ? t0[tid - d] : 0;
        __syncthreads();
        t0[tid] += t;
        __syncthreads();
    }
    int ex = t0[tid] - v;
    if (tid < nb) { bo[tid] = ex; bcur[tid] = ex; }
    if (tid == 511) bo[nb] = t0[511];
}

// ---------------- partition: bucket-grouped packed edges ----------------
__global__ __launch_bounds__(512) void partition_k(
    const void* __restrict__ ei, int* __restrict__ bcur,
    unsigned* __restrict__ ep, const int* __restrict__ flags,
    int nn, int ne, int nb) {
    __shared__ unsigned stage[CHUNK];    // 32 KB
    __shared__ u16 ab[CHUNK];            // 16 KB
    __shared__ int hist[512], incl[512], exl[512], gbase[512], lcur[512];
    int tid = threadIdx.x;
    int base = blockIdx.x * CHUNK;
    hist[tid] = 0;
    __syncthreads();
    int e64 = flags[7];
    unsigned pk[16]; int bk[16];
#pragma unroll
    for (int j = 0; j < 16; j++) {
        int e = base + j * 512 + tid;
        bk[j] = -1;
        pk[j] = 0;
        if (e < ne) {
            int src, dst;
            if (e64) {
                src = (int)((const long long*)ei)[e];
                dst = (int)((const long long*)ei)[(size_t)ne + e];
            } else {
                src = ((const int*)ei)[e];
                dst = ((const int*)ei)[(size_t)ne + e];
            }
            if ((unsigned)dst < (unsigned)nn) {
                if ((unsigned)src >= (unsigned)nn) src = 0;
                bk[j] = dst >> BSHIFT;
                pk[j] = (unsigned)src | ((unsigned)(dst & (BSIZE - 1)) << 17);
                atomicAdd(&hist[bk[j]], 1);
            }
        }
    }
    __syncthreads();
    incl[tid] = hist[tid];
    __syncthreads();
    for (int d = 1; d < 512; d <<= 1) {
        int t = (tid >= d) ? incl[tid - d] : 0;
        __syncthreads();
        incl[tid] += t;
        __syncthreads();
    }
    int ex = incl[tid] - hist[tid];
    exl[tid] = ex;
    lcur[tid] = ex;
    gbase[tid] = hist[tid] ? atomicAdd(&bcur[tid], hist[tid]) : 0;
    __syncthreads();
#pragma unroll
    for (int j = 0; j < 16; j++) {
        if (bk[j] >= 0) {
            int r = atomicAdd(&lcur[bk[j]], 1);
            stage[r] = pk[j];
            ab[r] = (u16)bk[j];
        }
    }
    __syncthreads();
    int tot = incl[511];
    for (int j = tid; j < tot; j += 512) {
        int b = ab[j];
        ep[gbase[b] + (j - exl[b])] = stage[j];
    }
}

// ---------------- per-bucket CSR finalize ----------------
__global__ __launch_bounds__(512) void csr_fill2(
    const unsigned* __restrict__ ep, const int* __restrict__ bo,
    int* __restrict__ off, int* __restrict__ cnt, int* __restrict__ esrc,
    int nn) {
    __shared__ int hist[BSIZE], incl[BSIZE], lcur[BSIZE];
    int b = blockIdx.x;
    int beg = bo[b], end = bo[b + 1];
    int tid = threadIdx.x;
    hist[tid] = 0;
    __syncthreads();
    for (int j = beg + tid; j < end; j += 512)
        atomicAdd(&hist[(ep[j] >> 17) & (BSIZE - 1)], 1);
    __syncthreads();
    incl[tid] = hist[tid];
    __syncthreads();
    for (int d = 1; d < 512; d <<= 1) {
        int t = (tid >= d) ? incl[tid - d] : 0;
        __syncthreads();
        incl[tid] += t;
        __syncthreads();
    }
    int ex = beg + incl[tid] - hist[tid];
    lcur[tid] = ex;
    int node = b * BSIZE + tid;
    if (node < nn) { off[node] = ex; cnt[node] = hist[tid]; }
    __syncthreads();
    for (int j = beg + tid; j < end; j += 512) {
        unsigned p = ep[j];
        int r = atomicAdd(&lcur[(p >> 17) & (BSIZE - 1)], 1);
        esrc[r] = (int)(p & 0x1FFFFu);
    }
}

// ---------------- layer 1 ----------------
// 512 thr = 32 nodes x 16 lanes (gather) = 8 waves (MFMA).
// Tile M=32,N=128,K=128. Fragment-major LDS (chunk=1KB, lane-contig reads).
// Split-K: wBh (16KB) holds W1l (kcg 0-1) then W1r (kcg 2-3).
// A idx (m,kcg): (mtile*4+kcg)*512 + (q*16+l15)*8 + w
// Bh idx (n,kc'): ((n>>4)*2+kc')*512 + (q*16+(n&15))*8 + w
__global__ __launch_bounds__(512, 8) void layer1(
    const void* __restrict__ x, const int* __restrict__ esrc,
    const int* __restrict__ off, const int* __restrict__ cnt,
    const void* __restrict__ W1l, const void* __restrict__ W1r,
    const void* __restrict__ b1, u16* __restrict__ h,
    const int* __restrict__ flags, int nn) {
    __shared__ __align__(16) u16 wA[8 * 512];    // 8 KB
    __shared__ __align__(16) u16 wBh[16 * 512];  // 16 KB (one K-half of W1)
    __shared__ float b_s[128];
    int tid = threadIdx.x;
    int node0 = blockIdx.x * 32;
    int xbf = flags[0];

    // ---- stage W1l (k 0..63, [64][128] row-major) into wBh ----
    if (flags[1]) {
        const ushort4* s = (const ushort4*)W1l;
        for (int i = tid; i < 2048; i += 512) {
            ushort4 v = s[i]; int k = i >> 5, n = (i & 31) * 4;
            int kc = k >> 5, q = (k >> 3) & 3, w = k & 7;
            int base = ((n >> 4) * 2 + kc) * 512 + (q * 16 + (n & 15)) * 8 + w;
            wBh[base] = v.x; wBh[base + 8] = v.y; wBh[base + 16] = v.z; wBh[base + 24] = v.w;
        }
    } else {
        const float4* s = (const float4*)W1l;
        for (int i = tid; i < 2048; i += 512) {
            float4 f = s[i]; int k = i >> 5, n = (i & 31) * 4;
            int kc = k >> 5, q = (k >> 3) & 3, w = k & 7;
            int base = ((n >> 4) * 2 + kc) * 512 + (q * 16 + (n & 15)) * 8 + w;
            wBh[base] = f2bf(f.x); wBh[base + 8] = f2bf(f.y);
            wBh[base + 16] = f2bf(f.z); wBh[base + 24] = f2bf(f.w);
        }
    }
    if (tid < 128) b_s[tid] = flags[3] ? bf2f(((const u16*)b1)[tid]) : ((const float*)b1)[tid];

    // ---- gather-mean (16 lanes/node, 4 feats/lane, unroll x8) ----
    int grp = tid >> 4, gl = tid & 15;
    int n = node0 + grp;
    int mtile = grp >> 4, l15m = grp & 15;
    int idx_mean = (mtile * 4 + (gl >> 3)) * 512 + (((gl >> 1) & 3) * 16 + l15m) * 8 + (gl & 1) * 4;
    int idx_x = (mtile * 4 + 2 + (gl >> 3)) * 512 + (((gl >> 1) & 3) * 16 + l15m) * 8 + (gl & 1) * 4;
    if (n < nn) {
        int beg = off[n], deg = cnt[n];
        float a0 = 0.f, a1 = 0.f, a2 = 0.f, a3 = 0.f;
        int i = 0;
        if (xbf) {
            const u16* xb = (const u16*)x + gl * 4;
            for (; i + 8 <= deg; i += 8) {
                ushort4 v[8];
#pragma unroll
                for (int j = 0; j < 8; j++) {
                    int s0 = esrc[beg + i + j];
                    v[j] = *(const ushort4*)(xb + (size_t)s0 * 64);
                }
#pragma unroll
                for (int j = 0; j < 8; j++) {
                    a0 += bf2f(v[j].x); a1 += bf2f(v[j].y);
                    a2 += bf2f(v[j].z); a3 += bf2f(v[j].w);
                }
            }
            for (; i < deg; i++) {
                int s0 = esrc[beg + i];
                ushort4 v = *(const ushort4*)(xb + (size_t)s0 * 64);
                a0 += bf2f(v.x); a1 += bf2f(v.y); a2 += bf2f(v.z); a3 += bf2f(v.w);
            }
        } else {
            const float* xb = (const float*)x + gl * 4;
            for (; i + 8 <= deg; i += 8) {
                float4 v[8];
#pragma unroll
                for (int j = 0; j < 8; j++) {
                    int s0 = esrc[beg + i + j];
                    v[j] = *(const float4*)(xb + (size_t)s0 * 64);
                }
#pragma unroll
                for (int j = 0; j < 8; j++) {
                    a0 += v[j].x; a1 += v[j].y; a2 += v[j].z; a3 += v[j].w;
                }
            }
            for (; i < deg; i++) {
                int s0 = esrc[beg + i];
                float4 v = *(const float4*)(xb + (size_t)s0 * 64);
                a0 += v.x; a1 += v.y; a2 += v.z; a3 += v.w;
            }
        }
        float inv = 1.0f / (float)(deg > 0 ? deg : 1);
        *(ushort4*)&wA[idx_mean] =
            make_ushort4(f2bf(a0 * inv), f2bf(a1 * inv), f2bf(a2 * inv), f2bf(a3 * inv));
        if (xbf) {
            *(ushort4*)&wA[idx_x] =
                *(const ushort4*)((const u16*)x + (size_t)n * 64 + gl * 4);
        } else {
            float4 xv = *(const float4*)((const float*)x + (size_t)n * 64 + gl * 4);
            *(ushort4*)&wA[idx_x] =
                make_ushort4(f2bf(xv.x), f2bf(xv.y), f2bf(xv.z), f2bf(xv.w));
        }
    } else {
        *(ushort4*)&wA[idx_mean] = make_ushort4(0, 0, 0, 0);
        *(ushort4*)&wA[idx_x] = make_ushort4(0, 0, 0, 0);
    }
    __syncthreads();

    // ---- MFMA half 0 (kcg 0-1, W1l) ----
    int wv = tid >> 6, lane = tid & 63;
    int l15 = lane & 15, q = lane >> 4;
    f32x4 acc0 = {0.f, 0.f, 0.f, 0.f};
    f32x4 acc1 = {0.f, 0.f, 0.f, 0.f};
#pragma unroll
    for (int kc = 0; kc < 2; kc++) {
        short8 a0 = *(const short8*)&wA[(kc) * 512 + lane * 8];
        short8 a1 = *(const short8*)&wA[(4 + kc) * 512 + lane * 8];
        short8 b  = *(const short8*)&wBh[(wv * 2 + kc) * 512 + lane * 8];
        acc0 = __builtin_amdgcn_mfma_f32_16x16x32_bf16(a0, b, acc0, 0, 0, 0);
        acc1 = __builtin_amdgcn_mfma_f32_16x16x32_bf16(a1, b, acc1, 0, 0, 0);
    }
    __syncthreads();   // all waves done reading wBh half 0

    // ---- stage W1r (k 0..63 of W1r = kcg 2-3) into wBh ----
    if (flags[2]) {
        const ushort4* s = (const ushort4*)W1r;
        for (int i = tid; i < 2048; i += 512) {
            ushort4 v = s[i]; int k = i >> 5, n = (i & 31) * 4;
            int kc = k >> 5, q2 = (k >> 3) & 3, w = k & 7;
            int base = ((n >> 4) * 2 + kc) * 512 + (q2 * 16 + (n & 15)) * 8 + w;
            wBh[base] = v.x; wBh[base + 8] = v.y; wBh[base + 16] = v.z; wBh[base + 24] = v.w;
        }
    } else {
        const float4* s = (const float4*)W1r;
        for (int i = tid; i < 2048; i += 512) {
            float4 f = s[i]; int k = i >> 5, n = (i & 31) * 4;
            int kc = k >> 5, q2 = (k >> 3) & 3, w = k & 7;
            int base = ((n >> 4) * 2 + kc) * 512 + (q2 * 16 + (n & 15)) * 8 + w;
            wBh[base] = f2bf(f.x); wBh[base + 8] = f2bf(f.y);
            wBh[base + 16] = f2bf(f.z); wBh[base + 24] = f2bf(f.w);
        }
    }
    __syncthreads();

    // ---- MFMA half 1 (kcg 2-3, W1r) ----
#pragma unroll
    for (int kc = 0; kc < 2; kc++) {
        short8 a0 = *(const short8*)&wA[(2 + kc) * 512 + lane * 8];
        short8 a1 = *(const short8*)&wA[(6 + kc) * 512 + lane * 8];
        short8 b  = *(const short8*)&wBh[(wv * 2 + kc) * 512 + lane * 8];
        acc0 = __builtin_amdgcn_mfma_f32_16x16x32_bf16(a0, b, acc0, 0, 0, 0);
        acc1 = __builtin_amdgcn_mfma_f32_16x16x32_bf16(a1, b, acc1, 0, 0, 0);
    }
    int nc = wv * 16 + l15;
    float bias = b_s[nc];
#pragma unroll
    for (int r = 0; r < 4; r++) {
        int m = q * 4 + r;
        int nd = node0 + m;
        if (nd < nn) h[(size_t)nd * 128 + nc] = f2bf(fmaxf(acc0[r] + bias, 0.0f));
        nd = node0 + 16 + m;
        if (nd < nn) h[(size_t)nd * 128 + nc] = f2bf(fmaxf(acc1[r] + bias, 0.0f));
    }
}

// ---------------- layer 2 ----------------
// Tile M=32,N=64,K=256. Split-K: wBh2 (16KB) holds W2l (kcg 0-3) then W2r (4-7).
// A idx (m,kcg): (mtile*8+kcg)*512 + (q*16+l15)*8 + w
// Bh idx (n,kc'): ((n>>4)*4+kc')*512 + (q*16+(n&15))*8 + w
__global__ __launch_bounds__(512, 8) void layer2(
    const u16* __restrict__ h, const int* __restrict__ esrc,
    const int* __restrict__ off, const int* __restrict__ cnt,
    const void* __restrict__ W2l, const void* __restrict__ W2r,
    const void* __restrict__ b2, void* __restrict__ out,
    const int* __restrict__ flags, int nn) {
    __shared__ __align__(16) u16 wA2[16 * 512];  // 16 KB
    __shared__ __align__(16) u16 wBh2[16 * 512]; // 16 KB (one K-half of W2)
    __shared__ float b_s[64];
    int tid = threadIdx.x;
    int node0 = blockIdx.x * 32;
    int obf = flags[0];

    // ---- stage W2l (k 0..127, [128][64] row-major) into wBh2 ----
    if (flags[4]) {
        const ushort4* s = (const ushort4*)W2l;
        for (int i = tid; i < 2048; i += 512) {
            ushort4 v = s[i]; int k = i >> 4, n = (i & 15) * 4;
            int kc = k >> 5, q = (k >> 3) & 3, w = k & 7;
            int base = ((n >> 4) * 4 + kc) * 512 + (q * 16 + (n & 15)) * 8 + w;
            wBh2[base] = v.x; wBh2[base + 8] = v.y; wBh2[base + 16] = v.z; wBh2[base + 24] = v.w;
        }
    } else {
        const float4* s = (const float4*)W2l;
        for (int i = tid; i < 2048; i += 512) {
            float4 f = s[i]; int k = i >> 4, n = (i & 15) * 4;
            int kc = k >> 5, q = (k >> 3) & 3, w = k & 7;
            int base = ((n >> 4) * 4 + kc) * 512 + (q * 16 + (n & 15)) * 8 + w;
            wBh2[base] = f2bf(f.x); wBh2[base + 8] = f2bf(f.y);
            wBh2[base + 16] = f2bf(f.z); wBh2[base + 24] = f2bf(f.w);
        }
    }
    if (tid < 64) b_s[tid] = flags[6] ? bf2f(((const u16*)b2)[tid]) : ((const float*)b2)[tid];

    // ---- gather-mean (16 lanes/node, 8 feats/lane, unroll x8) ----
    int grp = tid >> 4, gl = tid & 15;
    int n = node0 + grp;
    int mtile = grp >> 4, l15m = grp & 15;
    int idx_mean = (mtile * 8 + (gl >> 2)) * 512 + ((gl & 3) * 16 + l15m) * 8;
    int idx_h = (mtile * 8 + 4 + (gl >> 2)) * 512 + ((gl & 3) * 16 + l15m) * 8;
    if (n < nn) {
        int beg = off[n], deg = cnt[n];
        float a[8];
#pragma unroll
        for (int j = 0; j < 8; j++) a[j] = 0.0f;
        const u16* hb = h + (size_t)gl * 8;
        int i = 0;
        for (; i + 8 <= deg; i += 8) {
            uint4 v[8];
#pragma unroll
            for (int j = 0; j < 8; j++) {
                int s0 = esrc[beg + i + j];
                v[j] = *(const uint4*)(hb + (size_t)s0 * 128);
            }
#pragma unroll
            for (int j = 0; j < 8; j++) {
                a[0] += bfu_lo(v[j].x); a[1] += bfu_hi(v[j].x);
                a[2] += bfu_lo(v[j].y); a[3] += bfu_hi(v[j].y);
                a[4] += bfu_lo(v[j].z); a[5] += bfu_hi(v[j].z);
                a[6] += bfu_lo(v[j].w); a[7] += bfu_hi(v[j].w);
            }
        }
        for (; i < deg; i++) {
            int s0 = esrc[beg + i];
            uint4 v = *(const uint4*)(hb + (size_t)s0 * 128);
            a[0] += bfu_lo(v.x); a[1] += bfu_hi(v.x);
            a[2] += bfu_lo(v.y); a[3] += bfu_hi(v.y);
            a[4] += bfu_lo(v.z); a[5] += bfu_hi(v.z);
            a[6] += bfu_lo(v.w); a[7] += bfu_hi(v.w);
        }
        float inv = 1.0f / (float)(deg > 0 ? deg : 1);
        *(ushort4*)&wA2[idx_mean] =
            make_ushort4(f2bf(a[0] * inv), f2bf(a[1] * inv), f2bf(a[2] * inv), f2bf(a[3] * inv));
        *(ushort4*)&wA2[idx_mean + 4] =
            make_ushort4(f2bf(a[4] * inv), f2bf(a[5] * inv), f2bf(a[6] * inv), f2bf(a[7] * inv));
        uint4 hv = *(const uint4*)(h + (size_t)n * 128 + gl * 8);
        *(uint4*)&wA2[idx_h] = hv;
    } else {
        *(ushort4*)&wA2[idx_mean] = make_ushort4(0, 0, 0, 0);
        *(ushort4*)&wA2[idx_mean + 4] = make_ushort4(0, 0, 0, 0);
        *(uint4*)&wA2[idx_h] = make_uint4(0, 0, 0, 0);
    }
    __syncthreads();

    // ---- MFMA half 0 (kcg 0-3, W2l) ----
    int wv = tid >> 6, lane = tid & 63;
    int l15 = lane & 15, q = lane >> 4;
    int mt = wv >> 2, nt = wv & 3;
    f32x4 acc = {0.f, 0.f, 0.f, 0.f};
#pragma unroll
    for (int kc = 0; kc < 4; kc++) {
        short8 a = *(const short8*)&wA2[(mt * 8 + kc) * 512 + lane * 8];
        short8 b = *(const short8*)&wBh2[(nt * 4 + kc) * 512 + lane * 8];
        acc = __builtin_amdgcn_mfma_f32_16x16x32_bf16(a, b, acc, 0, 0, 0);
    }
    __syncthreads();   // all waves done reading wBh2 half 0

    // ---- stage W2r (kcg 4-7) into wBh2 ----
    if (flags[5]) {
        const ushort4* s = (const ushort4*)W2r;
        for (int i = tid; i < 2048; i += 512) {
            ushort4 v = s[i]; int k = i >> 4, n = (i & 15) * 4;
            int kc = k >> 5, q2 = (k >> 3) & 3, w = k & 7;
            int base = ((n >> 4) * 4 + kc) * 512 + (q2 * 16 + (n & 15)) * 8 + w;
            wBh2[base] = v.x; wBh2[base + 8] = v.y; wBh2[base + 16] = v.z; wBh2[base + 24] = v.w;
        }
    } else {
        const float4* s = (const float4*)W2r;
        for (int i = tid; i < 2048; i += 512) {
            float4 f = s[i]; int k = i >> 4, n = (i & 15) * 4;
            int kc = k >> 5, q2 = (k >> 3) & 3, w = k & 7;
            int base = ((n >> 4) * 4 + kc) * 512 + (q2 * 16 + (n & 15)) * 8 + w;
            wBh2[base] = f2bf(f.x); wBh2[base + 8] = f2bf(f.y);
            wBh2[base + 16] = f2bf(f.z); wBh2[base + 24] = f2bf(f.w);
        }
    }
    __syncthreads();

    // ---- MFMA half 1 (kcg 4-7, W2r) ----
#pragma unroll
    for (int kc = 0; kc < 4; kc++) {
        short8 a = *(const short8*)&wA2[(mt * 8 + 4 + kc) * 512 + lane * 8];
        short8 b = *(const short8*)&wBh2[(nt * 4 + kc) * 512 + lane * 8];
        acc = __builtin_amdgcn_mfma_f32_16x16x32_bf16(a, b, acc, 0, 0, 0);
    }
    int nc = nt * 16 + l15;
    float bias = b_s[nc];
#pragma unroll
    for (int r = 0; r < 4; r++) {
        int m = q * 4 + r;
        int nd = node0 + mt * 16 + m;
        if (nd < nn) {
            float v = acc[r] + bias;
            if (obf) ((u16*)out)[(size_t)nd * 64 + nc] = f2bf(v);
            else     ((float*)out)[(size_t)nd * 64 + nc] = v;
        }
    }
}

// ---------------- fallback ----------------
__global__ __launch_bounds__(256) void zero_out_k(u16* __restrict__ out, int n) {
    int i = blockIdx.x * 256 + threadIdx.x;
    if (i < n) out[i] = 0;
}

extern "C" void kernel_launch(void* const* d_in, const int* in_sizes, int n_in,
                              void* d_out, int out_size, void* d_ws, size_t ws_size,
                              hipStream_t stream) {
    const void* x   = d_in[0];
    const void* ei  = d_in[1];
    const void* W1l = d_in[2];
    const void* W1r = d_in[3];
    const void* b1  = d_in[4];
    const void* W2l = d_in[5];
    const void* W2r = d_in[6];
    const void* b2  = d_in[7];

    int nn = in_sizes[0] / 64;
    int ne = in_sizes[1] / 2;
    int nb = (nn + BSIZE - 1) / BSIZE;

    auto al = [](size_t v) { return (v + 255) & ~(size_t)255; };
    size_t o_flags = 0;
    size_t o_bcnt  = 256;
    size_t o_bo    = al(o_bcnt + 512 * 4);
    size_t o_bcur  = al(o_bo + 513 * 4);
    size_t o_cnt   = al(o_bcur + 512 * 4);
    size_t o_off   = al(o_cnt + (size_t)nn * 4);
    size_t o_esrc  = al(o_off + (size_t)nn * 4);
    size_t o_h     = al(o_esrc + (size_t)ne * 4);
    size_t ws_req  = o_h + (size_t)nn * 128 * 2;

    // ep (packed edges, ne*4 B) aliases the h region (h written after csr_fill2)
    bool ok = ws_size >= ws_req && nb >= 1 && nb <= 512 && nn <= 131072 &&
              (size_t)ne * 4 <= (size_t)nn * 256;
    if (!ok) {
        zero_out_k<<<(out_size + 255) / 256, 256, 0, stream>>>((u16*)d_out, out_size);
        return;
    }

    char* ws = (char*)d_ws;
    int* flags = (int*)(ws + o_flags);
    int* bcnt  = (int*)(ws + o_bcnt);
    int* bo    = (int*)(ws + o_bo);
    int* bcur  = (int*)(ws + o_bcur);
    int* cnt   = (int*)(ws + o_cnt);
    int* off   = (int*)(ws + o_off);
    int* esrc  = (int*)(ws + o_esrc);
    u16* h     = (u16*)(ws + o_h);
    unsigned* ep = (unsigned*)(ws + o_h);

    probe_k<<<1, 256, 0, stream>>>(x, W1l, W1r, b1, W2l, W2r, b2, ei, flags, ne,
                                   in_sizes[0], in_sizes[2], in_sizes[3], in_sizes[4],
                                   in_sizes[5], in_sizes[6], in_sizes[7]);
    hipMemsetAsync(bcnt, 0, 512 * 4, stream);
    bucket_count<<<512, 256, 0, stream>>>(ei, bcnt, flags, nn, ne, nb);
    scan_buckets<<<1, 512, 0, stream>>>(bcnt, bo, bcur, nb);
    int nchunk = (ne + CHUNK - 1) / CHUNK;
    partition_k<<<nchunk, 512, 0, stream>>>(ei, bcur, ep, flags, nn, ne, nb);
    csr_fill2<<<nb, 512, 0, stream>>>(ep, bo, off, cnt, esrc, nn);
    int lb = (nn + 31) / 32;
    layer1<<<lb, 512, 0, stream>>>(x, esrc, off, cnt, W1l, W1r, b1, h, flags, nn);
    layer2<<<lb, 512, 0, stream>>>(h, esrc, off, cnt, W2l, W2r, b2, d_out, flags, nn);
}

// Round 10
// 331.983 us; speedup vs baseline: 1.1212x; 1.1212x over previous
//
#include <hip/hip_runtime.h>
#include <hip/hip_bf16.h>
#include <stdint.h>

// GraphSAGE 2-layer encoder — bucketed CSR build + MFMA GEMM layers.
// R10 = R9 with launch_bounds(512,4): R9's (512,8) forced VGPR<=64 -> compiler
// spilled the gather pipeline to scratch (WRITE_SIZE 25->219MB, VGPR 44->32).
// Split-K staging (33KB LDS, 4 blocks/CU) retained; register budget restored.

typedef unsigned short u16;
typedef __attribute__((ext_vector_type(8))) short short8;   // bf16x8 A/B frag
typedef __attribute__((ext_vector_type(4))) float f32x4;    // fp32x4 C/D frag

#define BSHIFT 9
#define BSIZE  512          // nodes per bucket
#define CHUNK  8192         // edges per partition block

__device__ __forceinline__ float bf2f(u16 v) { return __uint_as_float(((uint32_t)v) << 16); }
__device__ __forceinline__ float bfu_lo(uint32_t u) { return __uint_as_float(u << 16); }
__device__ __forceinline__ float bfu_hi(uint32_t u) { return __uint_as_float(u & 0xffff0000u); }
__device__ __forceinline__ u16 f2bf(float f) {
    uint32_t u = __float_as_uint(f);
    return (u16)((u + 0x7fffu + ((u >> 16) & 1u)) >> 16);
}

// ---------------- probe: dtype flags ----------------
__global__ __launch_bounds__(256) void probe_k(
    const void* x, const void* w1l, const void* w1r, const void* b1,
    const void* w2l, const void* w2r, const void* b2, const void* ei,
    int* __restrict__ flags, int ne,
    int c0, int c1, int c2, int c3, int c4, int c5, int c6) {
    __shared__ int cs_s[8];
    int tid = threadIdx.x, a = tid >> 5, lane = tid & 31;
    if (tid < 8) cs_s[tid] = 0;
    __syncthreads();
    if (a < 7) {
        const void* ptrs[7] = {x, w1l, w1r, b1, w2l, w2r, b2};
        int cs[7] = {c0, c1, c2, c3, c4, c5, c6};
        int C = cs[a];
        int stride = C / 32; if (stride < 1) stride = 1;
        long long i = (long long)lane * stride;
        if (i > C - 1) i = C - 1;
        i &= ~1LL;
        u16 v = ((const u16*)ptrs[a])[i];
        int e = (v >> 7) & 0xFF;
        int sane = ((e >= 0x50 && e <= 0x97) || v == 0) ? 1 : 0;
        atomicAdd(&cs_s[a], sane);
    } else {
        long long n32 = 2LL * ne;
        long long stride = n32 / 32; if (stride < 1) stride = 1;
        long long i = (long long)lane * stride; i |= 1;
        if (i >= n32) i = 1;
        int wv = ((const int*)ei)[i];
        atomicAdd(&cs_s[7], wv != 0 ? 1 : 0);
    }
    __syncthreads();
    if (tid < 7) flags[tid] = (cs_s[tid] >= 24) ? 1 : 0;
    if (tid == 7) flags[7] = (cs_s[7] == 0) ? 1 : 0;
}

// ---------------- bucket histogram ----------------
__global__ __launch_bounds__(256) void bucket_count(
    const void* __restrict__ ei, int* __restrict__ bcnt,
    const int* __restrict__ flags, int nn, int ne, int nb) {
    __shared__ int hist[512];
    for (int i = threadIdx.x; i < 512; i += 256) hist[i] = 0;
    __syncthreads();
    int e64 = flags[7];
    int stride = gridDim.x * 256;
    for (int e = blockIdx.x * 256 + threadIdx.x; e < ne; e += stride) {
        int dst = e64 ? (int)((const long long*)ei)[(size_t)ne + e]
                      : ((const int*)ei)[(size_t)ne + e];
        if ((unsigned)dst < (unsigned)nn) atomicAdd(&hist[dst >> BSHIFT], 1);
    }
    __syncthreads();
    for (int i = threadIdx.x; i < nb; i += 256)
        if (hist[i]) atomicAdd(&bcnt[i], hist[i]);
}

// ---------------- bucket scan (parallel) ----------------
__global__ __launch_bounds__(512) void scan_buckets(
    const int* __restrict__ bcnt, int* __restrict__ bo,
    int* __restrict__ bcur, int nb) {
    __shared__ int t0[512];
    int tid = threadIdx.x;
    int v = (tid < nb) ? bcnt[tid] : 0;
    t0[tid] = v;
    __syncthreads();
    for (int d = 1; d < 512; d <<= 1) {
        int t = (tid >= d) ? t0[tid - d] : 0;
        __syncthreads();
        t0[tid] += t;
        __syncthreads();
    }
    int ex = t0[tid] - v;
    if (tid < nb) { bo[tid] = ex; bcur[tid] = ex; }
    if (tid == 511) bo[nb] = t0[511];
}

// ---------------- partition: bucket-grouped packed edges ----------------
__global__ __launch_bounds__(512) void partition_k(
    const void* __restrict__ ei, int* __restrict__ bcur,
    unsigned* __restrict__ ep, const int* __restrict__ flags,
    int nn, int ne, int nb) {
    __shared__ unsigned stage[CHUNK];    // 32 KB
    __shared__ u16 ab[CHUNK];            // 16 KB
    __shared__ int hist[512], incl[512], exl[512], gbase[512], lcur[512];
    int tid = threadIdx.x;
    int base = blockIdx.x * CHUNK;
    hist[tid] = 0;
    __syncthreads();
    int e64 = flags[7];
    unsigned pk[16]; int bk[16];
#pragma unroll
    for (int j = 0; j < 16; j++) {
        int e = base + j * 512 + tid;
        bk[j] = -1;
        pk[j] = 0;
        if (e < ne) {
            int src, dst;
            if (e64) {
                src = (int)((const long long*)ei)[e];
                dst = (int)((const long long*)ei)[(size_t)ne + e];
            } else {
                src = ((const int*)ei)[e];
                dst = ((const int*)ei)[(size_t)ne + e];
            }
            if ((unsigned)dst < (unsigned)nn) {
                if ((unsigned)src >= (unsigned)nn) src = 0;
                bk[j] = dst >> BSHIFT;
                pk[j] = (unsigned)src | ((unsigned)(dst & (BSIZE - 1)) << 17);
                atomicAdd(&hist[bk[j]], 1);
            }
        }
    }
    __syncthreads();
    incl[tid] = hist[tid];
    __syncthreads();
    for (int d = 1; d < 512; d <<= 1) {
        int t = (tid >= d) ? incl[tid - d] : 0;
        __syncthreads();
        incl[tid] += t;
        __syncthreads();
    }
    int ex = incl[tid] - hist[tid];
    exl[tid] = ex;
    lcur[tid] = ex;
    gbase[tid] = hist[tid] ? atomicAdd(&bcur[tid], hist[tid]) : 0;
    __syncthreads();
#pragma unroll
    for (int j = 0; j < 16; j++) {
        if (bk[j] >= 0) {
            int r = atomicAdd(&lcur[bk[j]], 1);
            stage[r] = pk[j];
            ab[r] = (u16)bk[j];
        }
    }
    __syncthreads();
    int tot = incl[511];
    for (int j = tid; j < tot; j += 512) {
        int b = ab[j];
        ep[gbase[b] + (j - exl[b])] = stage[j];
    }
}

// ---------------- per-bucket CSR finalize ----------------
__global__ __launch_bounds__(512) void csr_fill2(
    const unsigned* __restrict__ ep, const int* __restrict__ bo,
    int* __restrict__ off, int* __restrict__ cnt, int* __restrict__ esrc,
    int nn) {
    __shared__ int hist[BSIZE], incl[BSIZE], lcur[BSIZE];
    int b = blockIdx.x;
    int beg = bo[b], end = bo[b + 1];
    int tid = threadIdx.x;
    hist[tid] = 0;
    __syncthreads();
    for (int j = beg + tid; j < end; j += 512)
        atomicAdd(&hist[(ep[j] >> 17) & (BSIZE - 1)], 1);
    __syncthreads();
    incl[tid] = hist[tid];
    __syncthreads();
    for (int d = 1; d < 512; d <<= 1) {
        int t = (tid >= d) ? incl[tid - d] : 0;
        __syncthreads();
        incl[tid] += t;
        __syncthreads();
    }
    int ex = beg + incl[tid] - hist[tid];
    lcur[tid] = ex;
    int node = b * BSIZE + tid;
    if (node < nn) { off[node] = ex; cnt[node] = hist[tid]; }
    __syncthreads();
    for (int j = beg + tid; j < end; j += 512) {
        unsigned p = ep[j];
        int r = atomicAdd(&lcur[(p >> 17) & (BSIZE - 1)], 1);
        esrc[r] = (int)(p & 0x1FFFFu);
    }
}

// ---------------- layer 1 ----------------
// 512 thr = 32 nodes x 16 lanes (gather) = 8 waves (MFMA).
// Tile M=32,N=128,K=128. Fragment-major LDS; split-K wBh (16KB).
__global__ __launch_bounds__(512, 4) void layer1(
    const void* __restrict__ x, const int* __restrict__ esrc,
    const int* __restrict__ off, const int* __restrict__ cnt,
    const void* __restrict__ W1l, const void* __restrict__ W1r,
    const void* __restrict__ b1, u16* __restrict__ h,
    const int* __restrict__ flags, int nn) {
    __shared__ __align__(16) u16 wA[8 * 512];    // 8 KB
    __shared__ __align__(16) u16 wBh[16 * 512];  // 16 KB (one K-half of W1)
    __shared__ float b_s[128];
    int tid = threadIdx.x;
    int node0 = blockIdx.x * 32;
    int xbf = flags[0];

    // ---- stage W1l (k 0..63, [64][128] row-major) into wBh ----
    if (flags[1]) {
        const ushort4* s = (const ushort4*)W1l;
        for (int i = tid; i < 2048; i += 512) {
            ushort4 v = s[i]; int k = i >> 5, n = (i & 31) * 4;
            int kc = k >> 5, q = (k >> 3) & 3, w = k & 7;
            int base = ((n >> 4) * 2 + kc) * 512 + (q * 16 + (n & 15)) * 8 + w;
            wBh[base] = v.x; wBh[base + 8] = v.y; wBh[base + 16] = v.z; wBh[base + 24] = v.w;
        }
    } else {
        const float4* s = (const float4*)W1l;
        for (int i = tid; i < 2048; i += 512) {
            float4 f = s[i]; int k = i >> 5, n = (i & 31) * 4;
            int kc = k >> 5, q = (k >> 3) & 3, w = k & 7;
            int base = ((n >> 4) * 2 + kc) * 512 + (q * 16 + (n & 15)) * 8 + w;
            wBh[base] = f2bf(f.x); wBh[base + 8] = f2bf(f.y);
            wBh[base + 16] = f2bf(f.z); wBh[base + 24] = f2bf(f.w);
        }
    }
    if (tid < 128) b_s[tid] = flags[3] ? bf2f(((const u16*)b1)[tid]) : ((const float*)b1)[tid];

    // ---- gather-mean (16 lanes/node, 4 feats/lane, unroll x8) ----
    int grp = tid >> 4, gl = tid & 15;
    int n = node0 + grp;
    int mtile = grp >> 4, l15m = grp & 15;
    int idx_mean = (mtile * 4 + (gl >> 3)) * 512 + (((gl >> 1) & 3) * 16 + l15m) * 8 + (gl & 1) * 4;
    int idx_x = (mtile * 4 + 2 + (gl >> 3)) * 512 + (((gl >> 1) & 3) * 16 + l15m) * 8 + (gl & 1) * 4;
    if (n < nn) {
        int beg = off[n], deg = cnt[n];
        float a0 = 0.f, a1 = 0.f, a2 = 0.f, a3 = 0.f;
        int i = 0;
        if (xbf) {
            const u16* xb = (const u16*)x + gl * 4;
            for (; i + 8 <= deg; i += 8) {
                ushort4 v[8];
#pragma unroll
                for (int j = 0; j < 8; j++) {
                    int s0 = esrc[beg + i + j];
                    v[j] = *(const ushort4*)(xb + (size_t)s0 * 64);
                }
#pragma unroll
                for (int j = 0; j < 8; j++) {
                    a0 += bf2f(v[j].x); a1 += bf2f(v[j].y);
                    a2 += bf2f(v[j].z); a3 += bf2f(v[j].w);
                }
            }
            for (; i < deg; i++) {
                int s0 = esrc[beg + i];
                ushort4 v = *(const ushort4*)(xb + (size_t)s0 * 64);
                a0 += bf2f(v.x); a1 += bf2f(v.y); a2 += bf2f(v.z); a3 += bf2f(v.w);
            }
        } else {
            const float* xb = (const float*)x + gl * 4;
            for (; i + 8 <= deg; i += 8) {
                float4 v[8];
#pragma unroll
                for (int j = 0; j < 8; j++) {
                    int s0 = esrc[beg + i + j];
                    v[j] = *(const float4*)(xb + (size_t)s0 * 64);
                }
#pragma unroll
                for (int j = 0; j < 8; j++) {
                    a0 += v[j].x; a1 += v[j].y; a2 += v[j].z; a3 += v[j].w;
                }
            }
            for (; i < deg; i++) {
                int s0 = esrc[beg + i];
                float4 v = *(const float4*)(xb + (size_t)s0 * 64);
                a0 += v.x; a1 += v.y; a2 += v.z; a3 += v.w;
            }
        }
        float inv = 1.0f / (float)(deg > 0 ? deg : 1);
        *(ushort4*)&wA[idx_mean] =
            make_ushort4(f2bf(a0 * inv), f2bf(a1 * inv), f2bf(a2 * inv), f2bf(a3 * inv));
        if (xbf) {
            *(ushort4*)&wA[idx_x] =
                *(const ushort4*)((const u16*)x + (size_t)n * 64 + gl * 4);
        } else {
            float4 xv = *(const float4*)((const float*)x + (size_t)n * 64 + gl * 4);
            *(ushort4*)&wA[idx_x] =
                make_ushort4(f2bf(xv.x), f2bf(xv.y), f2bf(xv.z), f2bf(xv.w));
        }
    } else {
        *(ushort4*)&wA[idx_mean] = make_ushort4(0, 0, 0, 0);
        *(ushort4*)&wA[idx_x] = make_ushort4(0, 0, 0, 0);
    }
    __syncthreads();

    // ---- MFMA half 0 (kcg 0-1, W1l) ----
    int wv = tid >> 6, lane = tid & 63;
    int l15 = lane & 15, q = lane >> 4;
    f32x4 acc0 = {0.f, 0.f, 0.f, 0.f};
    f32x4 acc1 = {0.f, 0.f, 0.f, 0.f};
#pragma unroll
    for (int kc = 0; kc < 2; kc++) {
        short8 a0 = *(const short8*)&wA[(kc) * 512 + lane * 8];
        short8 a1 = *(const short8*)&wA[(4 + kc) * 512 + lane * 8];
        short8 b  = *(const short8*)&wBh[(wv * 2 + kc) * 512 + lane * 8];
        acc0 = __builtin_amdgcn_mfma_f32_16x16x32_bf16(a0, b, acc0, 0, 0, 0);
        acc1 = __builtin_amdgcn_mfma_f32_16x16x32_bf16(a1, b, acc1, 0, 0, 0);
    }
    __syncthreads();   // all waves done reading wBh half 0

    // ---- stage W1r (kcg 2-3) into wBh ----
    if (flags[2]) {
        const ushort4* s = (const ushort4*)W1r;
        for (int i = tid; i < 2048; i += 512) {
            ushort4 v = s[i]; int k = i >> 5, n = (i & 31) * 4;
            int kc = k >> 5, q2 = (k >> 3) & 3, w = k & 7;
            int base = ((n >> 4) * 2 + kc) * 512 + (q2 * 16 + (n & 15)) * 8 + w;
            wBh[base] = v.x; wBh[base + 8] = v.y; wBh[base + 16] = v.z; wBh[base + 24] = v.w;
        }
    } else {
        const float4* s = (const float4*)W1r;
        for (int i = tid; i < 2048; i += 512) {
            float4 f = s[i]; int k = i >> 5, n = (i & 31) * 4;
            int kc = k >> 5, q2 = (k >> 3) & 3, w = k & 7;
            int base = ((n >> 4) * 2 + kc) * 512 + (q2 * 16 + (n & 15)) * 8 + w;
            wBh[base] = f2bf(f.x); wBh[base + 8] = f2bf(f.y);
            wBh[base + 16] = f2bf(f.z); wBh[base + 24] = f2bf(f.w);
        }
    }
    __syncthreads();

    // ---- MFMA half 1 (kcg 2-3, W1r) ----
#pragma unroll
    for (int kc = 0; kc < 2; kc++) {
        short8 a0 = *(const short8*)&wA[(2 + kc) * 512 + lane * 8];
        short8 a1 = *(const short8*)&wA[(6 + kc) * 512 + lane * 8];
        short8 b  = *(const short8*)&wBh[(wv * 2 + kc) * 512 + lane * 8];
        acc0 = __builtin_amdgcn_mfma_f32_16x16x32_bf16(a0, b, acc0, 0, 0, 0);
        acc1 = __builtin_amdgcn_mfma_f32_16x16x32_bf16(a1, b, acc1, 0, 0, 0);
    }
    int nc = wv * 16 + l15;
    float bias = b_s[nc];
#pragma unroll
    for (int r = 0; r < 4; r++) {
        int m = q * 4 + r;
        int nd = node0 + m;
        if (nd < nn) h[(size_t)nd * 128 + nc] = f2bf(fmaxf(acc0[r] + bias, 0.0f));
        nd = node0 + 16 + m;
        if (nd < nn) h[(size_t)nd * 128 + nc] = f2bf(fmaxf(acc1[r] + bias, 0.0f));
    }
}

// ---------------- layer 2 ----------------
// Tile M=32,N=64,K=256. Split-K: wBh2 (16KB) holds W2l (kcg 0-3) then W2r (4-7).
__global__ __launch_bounds__(512, 4) void layer2(
    const u16* __restrict__ h, const int* __restrict__ esrc,
    const int* __restrict__ off, const int* __restrict__ cnt,
    const void* __restrict__ W2l, const void* __restrict__ W2r,
    const void* __restrict__ b2, void* __restrict__ out,
    const int* __restrict__ flags, int nn) {
    __shared__ __align__(16) u16 wA2[16 * 512];  // 16 KB
    __shared__ __align__(16) u16 wBh2[16 * 512]; // 16 KB (one K-half of W2)
    __shared__ float b_s[64];
    int tid = threadIdx.x;
    int node0 = blockIdx.x * 32;
    int obf = flags[0];

    // ---- stage W2l (k 0..127, [128][64] row-major) into wBh2 ----
    if (flags[4]) {
        const ushort4* s = (const ushort4*)W2l;
        for (int i = tid; i < 2048; i += 512) {
            ushort4 v = s[i]; int k = i >> 4, n = (i & 15) * 4;
            int kc = k >> 5, q = (k >> 3) & 3, w = k & 7;
            int base = ((n >> 4) * 4 + kc) * 512 + (q * 16 + (n & 15)) * 8 + w;
            wBh2[base] = v.x; wBh2[base + 8] = v.y; wBh2[base + 16] = v.z; wBh2[base + 24] = v.w;
        }
    } else {
        const float4* s = (const float4*)W2l;
        for (int i = tid; i < 2048; i += 512) {
            float4 f = s[i]; int k = i >> 4, n = (i & 15) * 4;
            int kc = k >> 5, q = (k >> 3) & 3, w = k & 7;
            int base = ((n >> 4) * 4 + kc) * 512 + (q * 16 + (n & 15)) * 8 + w;
            wBh2[base] = f2bf(f.x); wBh2[base + 8] = f2bf(f.y);
            wBh2[base + 16] = f2bf(f.z); wBh2[base + 24] = f2bf(f.w);
        }
    }
    if (tid < 64) b_s[tid] = flags[6] ? bf2f(((const u16*)b2)[tid]) : ((const float*)b2)[tid];

    // ---- gather-mean (16 lanes/node, 8 feats/lane, unroll x8) ----
    int grp = tid >> 4, gl = tid & 15;
    int n = node0 + grp;
    int mtile = grp >> 4, l15m = grp & 15;
    int idx_mean = (mtile * 8 + (gl >> 2)) * 512 + ((gl & 3) * 16 + l15m) * 8;
    int idx_h = (mtile * 8 + 4 + (gl >> 2)) * 512 + ((gl & 3) * 16 + l15m) * 8;
    if (n < nn) {
        int beg = off[n], deg = cnt[n];
        float a[8];
#pragma unroll
        for (int j = 0; j < 8; j++) a[j] = 0.0f;
        const u16* hb = h + (size_t)gl * 8;
        int i = 0;
        for (; i + 8 <= deg; i += 8) {
            uint4 v[8];
#pragma unroll
            for (int j = 0; j < 8; j++) {
                int s0 = esrc[beg + i + j];
                v[j] = *(const uint4*)(hb + (size_t)s0 * 128);
            }
#pragma unroll
            for (int j = 0; j < 8; j++) {
                a[0] += bfu_lo(v[j].x); a[1] += bfu_hi(v[j].x);
                a[2] += bfu_lo(v[j].y); a[3] += bfu_hi(v[j].y);
                a[4] += bfu_lo(v[j].z); a[5] += bfu_hi(v[j].z);
                a[6] += bfu_lo(v[j].w); a[7] += bfu_hi(v[j].w);
            }
        }
        for (; i < deg; i++) {
            int s0 = esrc[beg + i];
            uint4 v = *(const uint4*)(hb + (size_t)s0 * 128);
            a[0] += bfu_lo(v.x); a[1] += bfu_hi(v.x);
            a[2] += bfu_lo(v.y); a[3] += bfu_hi(v.y);
            a[4] += bfu_lo(v.z); a[5] += bfu_hi(v.z);
            a[6] += bfu_lo(v.w); a[7] += bfu_hi(v.w);
        }
        float inv = 1.0f / (float)(deg > 0 ? deg : 1);
        *(ushort4*)&wA2[idx_mean] =
            make_ushort4(f2bf(a[0] * inv), f2bf(a[1] * inv), f2bf(a[2] * inv), f2bf(a[3] * inv));
        *(ushort4*)&wA2[idx_mean + 4] =
            make_ushort4(f2bf(a[4] * inv), f2bf(a[5] * inv), f2bf(a[6] * inv), f2bf(a[7] * inv));
        uint4 hv = *(const uint4*)(h + (size_t)n * 128 + gl * 8);
        *(uint4*)&wA2[idx_h] = hv;
    } else {
        *(ushort4*)&wA2[idx_mean] = make_ushort4(0, 0, 0, 0);
        *(ushort4*)&wA2[idx_mean + 4] = make_ushort4(0, 0, 0, 0);
        *(uint4*)&wA2[idx_h] = make_uint4(0, 0, 0, 0);
    }
    __syncthreads();

    // ---- MFMA half 0 (kcg 0-3, W2l) ----
    int wv = tid >> 6, lane = tid & 63;
    int l15 = lane & 15, q = lane >> 4;
    int mt = wv >> 2, nt = wv & 3;
    f32x4 acc = {0.f, 0.f, 0.f, 0.f};
#pragma unroll
    for (int kc = 0; kc < 4; kc++) {
        short8 a = *(const short8*)&wA2[(mt * 8 + kc) * 512 + lane * 8];
        short8 b = *(const short8*)&wBh2[(nt * 4 + kc) * 512 + lane * 8];
        acc = __builtin_amdgcn_mfma_f32_16x16x32_bf16(a, b, acc, 0, 0, 0);
    }
    __syncthreads();   // all waves done reading wBh2 half 0

    // ---- stage W2r (kcg 4-7) into wBh2 ----
    if (flags[5]) {
        const ushort4* s = (const ushort4*)W2r;
        for (int i = tid; i < 2048; i += 512) {
            ushort4 v = s[i]; int k = i >> 4, n = (i & 15) * 4;
            int kc = k >> 5, q2 = (k >> 3) & 3, w = k & 7;
            int base = ((n >> 4) * 4 + kc) * 512 + (q2 * 16 + (n & 15)) * 8 + w;
            wBh2[base] = v.x; wBh2[base + 8] = v.y; wBh2[base + 16] = v.z; wBh2[base + 24] = v.w;
        }
    } else {
        const float4* s = (const float4*)W2r;
        for (int i = tid; i < 2048; i += 512) {
            float4 f = s[i]; int k = i >> 4, n = (i & 15) * 4;
            int kc = k >> 5, q2 = (k >> 3) & 3, w = k & 7;
            int base = ((n >> 4) * 4 + kc) * 512 + (q2 * 16 + (n & 15)) * 8 + w;
            wBh2[base] = f2bf(f.x); wBh2[base + 8] = f2bf(f.y);
            wBh2[base + 16] = f2bf(f.z); wBh2[base + 24] = f2bf(f.w);
        }
    }
    __syncthreads();

    // ---- MFMA half 1 (kcg 4-7, W2r) ----
#pragma unroll
    for (int kc = 0; kc < 4; kc++) {
        short8 a = *(const short8*)&wA2[(mt * 8 + 4 + kc) * 512 + lane * 8];
        short8 b = *(const short8*)&wBh2[(nt * 4 + kc) * 512 + lane * 8];
        acc = __builtin_amdgcn_mfma_f32_16x16x32_bf16(a, b, acc, 0, 0, 0);
    }
    int nc = nt * 16 + l15;
    float bias = b_s[nc];
#pragma unroll
    for (int r = 0; r < 4; r++) {
        int m = q * 4 + r;
        int nd = node0 + mt * 16 + m;
        if (nd < nn) {
            float v = acc[r] + bias;
            if (obf) ((u16*)out)[(size_t)nd * 64 + nc] = f2bf(v);
            else     ((float*)out)[(size_t)nd * 64 + nc] = v;
        }
    }
}

// ---------------- fallback ----------------
__global__ __launch_bounds__(256) void zero_out_k(u16* __restrict__ out, int n) {
    int i = blockIdx.x * 256 + threadIdx.x;
    if (i < n) out[i] = 0;
}

extern "C" void kernel_launch(void* const* d_in, const int* in_sizes, int n_in,
                              void* d_out, int out_size, void* d_ws, size_t ws_size,
                              hipStream_t stream) {
    const void* x   = d_in[0];
    const void* ei  = d_in[1];
    const void* W1l = d_in[2];
    const void* W1r = d_in[3];
    const void* b1  = d_in[4];
    const void* W2l = d_in[5];
    const void* W2r = d_in[6];
    const void* b2  = d_in[7];

    int nn = in_sizes[0] / 64;
    int ne = in_sizes[1] / 2;
    int nb = (nn + BSIZE - 1) / BSIZE;

    auto al = [](size_t v) { return (v + 255) & ~(size_t)255; };
    size_t o_flags = 0;
    size_t o_bcnt  = 256;
    size_t o_bo    = al(o_bcnt + 512 * 4);
    size_t o_bcur  = al(o_bo + 513 * 4);
    size_t o_cnt   = al(o_bcur + 512 * 4);
    size_t o_off   = al(o_cnt + (size_t)nn * 4);
    size_t o_esrc  = al(o_off + (size_t)nn * 4);
    size_t o_h     = al(o_esrc + (size_t)ne * 4);
    size_t ws_req  = o_h + (size_t)nn * 128 * 2;

    // ep (packed edges, ne*4 B) aliases the h region (h written after csr_fill2)
    bool ok = ws_size >= ws_req && nb >= 1 && nb <= 512 && nn <= 131072 &&
              (size_t)ne * 4 <= (size_t)nn * 256;
    if (!ok) {
        zero_out_k<<<(out_size + 255) / 256, 256, 0, stream>>>((u16*)d_out, out_size);
        return;
    }

    char* ws = (char*)d_ws;
    int* flags = (int*)(ws + o_flags);
    int* bcnt  = (int*)(ws + o_bcnt);
    int* bo    = (int*)(ws + o_bo);
    int* bcur  = (int*)(ws + o_bcur);
    int* cnt   = (int*)(ws + o_cnt);
    int* off   = (int*)(ws + o_off);
    int* esrc  = (int*)(ws + o_esrc);
    u16* h     = (u16*)(ws + o_h);
    unsigned* ep = (unsigned*)(ws + o_h);

    probe_k<<<1, 256, 0, stream>>>(x, W1l, W1r, b1, W2l, W2r, b2, ei, flags, ne,
                                   in_sizes[0], in_sizes[2], in_sizes[3], in_sizes[4],
                                   in_sizes[5], in_sizes[6], in_sizes[7]);
    hipMemsetAsync(bcnt, 0, 512 * 4, stream);
    bucket_count<<<512, 256, 0, stream>>>(ei, bcnt, flags, nn, ne, nb);
    scan_buckets<<<1, 512, 0, stream>>>(bcnt, bo, bcur, nb);
    int nchunk = (ne + CHUNK - 1) / CHUNK;
    partition_k<<<nchunk, 512, 0, stream>>>(ei, bcur, ep, flags, nn, ne, nb);
    csr_fill2<<<nb, 512, 0, stream>>>(ep, bo, off, cnt, esrc, nn);
    int lb = (nn + 31) / 32;
    layer1<<<lb, 512, 0, stream>>>(x, esrc, off, cnt, W1l, W1r, b1, h, flags, nn);
    layer2<<<lb, 512, 0, stream>>>(h, esrc, off, cnt, W2l, W2r, b2, d_out, flags, nn);
}

// Round 11
// 299.824 us; speedup vs baseline: 1.2415x; 1.1073x over previous
//
#include <hip/hip_runtime.h>
#include <hip/hip_bf16.h>
#include <stdint.h>

// GraphSAGE 2-layer encoder — atomic-free bucketed CSR build + R8 MFMA layers.
// R11: layers reverted to R8 (best known: fragment-major LDS, full-weight
// staging, launch_bounds(512,4)). CSR build made deterministic:
//   count_chunks : per-chunk LDS hist -> hist2d[bucket][chunk]  (no atomics)
//   scan2d       : per-bucket scan over chunks -> base2d + btot
//   scan_buckets : scan btot -> bo
//   partition_k  : gbase = bo[b] + base2d[b][chunk]  (global atomics GONE)
//   csr_fill2    : unchanged
// hist2d/base2d overlay the h region after ep (all dead before layer1).

typedef unsigned short u16;
typedef __attribute__((ext_vector_type(8))) short short8;   // bf16x8 A/B frag
typedef __attribute__((ext_vector_type(4))) float f32x4;    // fp32x4 C/D frag

#define BSHIFT 9
#define BSIZE  512          // nodes per bucket
#define CHUNK  8192         // edges per partition block
#define NCP    256          // padded chunks-per-bucket stride (nchunk <= 256)

__device__ __forceinline__ float bf2f(u16 v) { return __uint_as_float(((uint32_t)v) << 16); }
__device__ __forceinline__ float bfu_lo(uint32_t u) { return __uint_as_float(u << 16); }
__device__ __forceinline__ float bfu_hi(uint32_t u) { return __uint_as_float(u & 0xffff0000u); }
__device__ __forceinline__ u16 f2bf(float f) {
    uint32_t u = __float_as_uint(f);
    return (u16)((u + 0x7fffu + ((u >> 16) & 1u)) >> 16);
}

// ---------------- probe: dtype flags ----------------
__global__ __launch_bounds__(256) void probe_k(
    const void* x, const void* w1l, const void* w1r, const void* b1,
    const void* w2l, const void* w2r, const void* b2, const void* ei,
    int* __restrict__ flags, int ne,
    int c0, int c1, int c2, int c3, int c4, int c5, int c6) {
    __shared__ int cs_s[8];
    int tid = threadIdx.x, a = tid >> 5, lane = tid & 31;
    if (tid < 8) cs_s[tid] = 0;
    __syncthreads();
    if (a < 7) {
        const void* ptrs[7] = {x, w1l, w1r, b1, w2l, w2r, b2};
        int cs[7] = {c0, c1, c2, c3, c4, c5, c6};
        int C = cs[a];
        int stride = C / 32; if (stride < 1) stride = 1;
        long long i = (long long)lane * stride;
        if (i > C - 1) i = C - 1;
        i &= ~1LL;
        u16 v = ((const u16*)ptrs[a])[i];
        int e = (v >> 7) & 0xFF;
        int sane = ((e >= 0x50 && e <= 0x97) || v == 0) ? 1 : 0;
        atomicAdd(&cs_s[a], sane);
    } else {
        long long n32 = 2LL * ne;
        long long stride = n32 / 32; if (stride < 1) stride = 1;
        long long i = (long long)lane * stride; i |= 1;
        if (i >= n32) i = 1;
        int wv = ((const int*)ei)[i];
        atomicAdd(&cs_s[7], wv != 0 ? 1 : 0);
    }
    __syncthreads();
    if (tid < 7) flags[tid] = (cs_s[tid] >= 24) ? 1 : 0;
    if (tid == 7) flags[7] = (cs_s[7] == 0) ? 1 : 0;
}

// ---------------- per-chunk bucket histogram (no global atomics) ----------
__global__ __launch_bounds__(512) void count_chunks(
    const void* __restrict__ ei, int* __restrict__ hist2d,
    const int* __restrict__ flags, int nn, int ne, int nb) {
    __shared__ int hist[512];
    int tid = threadIdx.x;
    hist[tid] = 0;
    __syncthreads();
    int e64 = flags[7];
    int base = blockIdx.x * CHUNK;
#pragma unroll
    for (int j = 0; j < 16; j++) {
        int e = base + j * 512 + tid;
        if (e < ne) {
            int dst = e64 ? (int)((const long long*)ei)[(size_t)ne + e]
                          : ((const int*)ei)[(size_t)ne + e];
            if ((unsigned)dst < (unsigned)nn) atomicAdd(&hist[dst >> BSHIFT], 1);
        }
    }
    __syncthreads();
    for (int b = tid; b < nb; b += 512)
        hist2d[b * NCP + blockIdx.x] = hist[b];
}

// ---------------- per-bucket scan over chunks ----------------
__global__ __launch_bounds__(256) void scan2d(
    const int* __restrict__ hist2d, int* __restrict__ base2d,
    int* __restrict__ btot, int nchunk) {
    __shared__ int t0[256];
    int b = blockIdx.x, tid = threadIdx.x;
    int v = (tid < nchunk) ? hist2d[b * NCP + tid] : 0;
    t0[tid] = v;
    __syncthreads();
    for (int d = 1; d < 256; d <<= 1) {
        int t = (tid >= d) ? t0[tid - d] : 0;
        __syncthreads();
        t0[tid] += t;
        __syncthreads();
    }
    if (tid < nchunk) base2d[b * NCP + tid] = t0[tid] - v;
    if (tid == 255) btot[b] = t0[255];
}

// ---------------- bucket scan ----------------
__global__ __launch_bounds__(512) void scan_buckets(
    const int* __restrict__ btot, int* __restrict__ bo, int nb) {
    __shared__ int t0[512];
    int tid = threadIdx.x;
    int v = (tid < nb) ? btot[tid] : 0;
    t0[tid] = v;
    __syncthreads();
    for (int d = 1; d < 512; d <<= 1) {
        int t = (tid >= d) ? t0[tid - d] : 0;
        __syncthreads();
        t0[tid] += t;
        __syncthreads();
    }
    if (tid < nb) bo[tid] = t0[tid] - v;
    if (tid == 511) bo[nb] = t0[511];
}

// ---------------- partition: bucket-grouped packed edges, atomic-free -----
__global__ __launch_bounds__(512) void partition_k(
    const void* __restrict__ ei, const int* __restrict__ bo,
    const int* __restrict__ base2d,
    unsigned* __restrict__ ep, const int* __restrict__ flags,
    int nn, int ne, int nb) {
    __shared__ unsigned stage[CHUNK];    // 32 KB
    __shared__ u16 ab[CHUNK];            // 16 KB
    __shared__ int hist[512], incl[512], exl[512], gbase[512], lcur[512];
    int tid = threadIdx.x;
    int base = blockIdx.x * CHUNK;
    hist[tid] = 0;
    __syncthreads();
    int e64 = flags[7];
    unsigned pk[16]; int bk[16];
#pragma unroll
    for (int j = 0; j < 16; j++) {
        int e = base + j * 512 + tid;
        bk[j] = -1;
        pk[j] = 0;
        if (e < ne) {
            int src, dst;
            if (e64) {
                src = (int)((const long long*)ei)[e];
                dst = (int)((const long long*)ei)[(size_t)ne + e];
            } else {
                src = ((const int*)ei)[e];
                dst = ((const int*)ei)[(size_t)ne + e];
            }
            if ((unsigned)dst < (unsigned)nn) {
                if ((unsigned)src >= (unsigned)nn) src = 0;
                bk[j] = dst >> BSHIFT;
                pk[j] = (unsigned)src | ((unsigned)(dst & (BSIZE - 1)) << 17);
                atomicAdd(&hist[bk[j]], 1);
            }
        }
    }
    __syncthreads();
    incl[tid] = hist[tid];
    __syncthreads();
    for (int d = 1; d < 512; d <<= 1) {
        int t = (tid >= d) ? incl[tid - d] : 0;
        __syncthreads();
        incl[tid] += t;
        __syncthreads();
    }
    int ex = incl[tid] - hist[tid];
    exl[tid] = ex;
    lcur[tid] = ex;
    gbase[tid] = (tid < nb) ? (bo[tid] + base2d[tid * NCP + blockIdx.x]) : 0;
    __syncthreads();
#pragma unroll
    for (int j = 0; j < 16; j++) {
        if (bk[j] >= 0) {
            int r = atomicAdd(&lcur[bk[j]], 1);
            stage[r] = pk[j];
            ab[r] = (u16)bk[j];
        }
    }
    __syncthreads();
    int tot = incl[511];
    for (int j = tid; j < tot; j += 512) {
        int b = ab[j];
        ep[gbase[b] + (j - exl[b])] = stage[j];
    }
}

// ---------------- per-bucket CSR finalize ----------------
__global__ __launch_bounds__(512) void csr_fill2(
    const unsigned* __restrict__ ep, const int* __restrict__ bo,
    int* __restrict__ off, int* __restrict__ cnt, int* __restrict__ esrc,
    int nn) {
    __shared__ int hist[BSIZE], incl[BSIZE], lcur[BSIZE];
    int b = blockIdx.x;
    int beg = bo[b], end = bo[b + 1];
    int tid = threadIdx.x;
    hist[tid] = 0;
    __syncthreads();
    for (int j = beg + tid; j < end; j += 512)
        atomicAdd(&hist[(ep[j] >> 17) & (BSIZE - 1)], 1);
    __syncthreads();
    incl[tid] = hist[tid];
    __syncthreads();
    for (int d = 1; d < 512; d <<= 1) {
        int t = (tid >= d) ? incl[tid - d] : 0;
        __syncthreads();
        incl[tid] += t;
        __syncthreads();
    }
    int ex = beg + incl[tid] - hist[tid];
    lcur[tid] = ex;
    int node = b * BSIZE + tid;
    if (node < nn) { off[node] = ex; cnt[node] = hist[tid]; }
    __syncthreads();
    for (int j = beg + tid; j < end; j += 512) {
        unsigned p = ep[j];
        int r = atomicAdd(&lcur[(p >> 17) & (BSIZE - 1)], 1);
        esrc[r] = (int)(p & 0x1FFFFu);
    }
}

// ---------------- layer 1 (R8 structure) ----------------
// 512 thr = 32 nodes x 16 lanes (gather) = 8 waves (MFMA).
// Tile M=32,N=128,K=128. Fragment-major LDS: chunk(tile,kc)=1KB, lane-contig.
__global__ __launch_bounds__(512, 4) void layer1(
    const void* __restrict__ x, const int* __restrict__ esrc,
    const int* __restrict__ off, const int* __restrict__ cnt,
    const void* __restrict__ W1l, const void* __restrict__ W1r,
    const void* __restrict__ b1, u16* __restrict__ h,
    const int* __restrict__ flags, int nn) {
    __shared__ __align__(16) u16 wB[32 * 512];   // 32 KB, chunks (ntile*4+kc)
    __shared__ __align__(16) u16 wA[8 * 512];    // 8 KB,  chunks (mtile*4+kc)
    __shared__ float b_s[128];
    int tid = threadIdx.x;
    int node0 = blockIdx.x * 32;
    int xbf = flags[0];

    if (flags[1]) {
        const ushort4* s = (const ushort4*)W1l;
        for (int i = tid; i < 2048; i += 512) {
            ushort4 v = s[i]; int k = i >> 5, n = (i & 31) * 4;
            int k8 = k >> 3, kc = k8 >> 2, q = k8 & 3, w = k & 7;
            int base = ((n >> 4) * 4 + kc) * 512 + (q * 16 + (n & 15)) * 8 + w;
            wB[base] = v.x; wB[base + 8] = v.y; wB[base + 16] = v.z; wB[base + 24] = v.w;
        }
    } else {
        const float4* s = (const float4*)W1l;
        for (int i = tid; i < 2048; i += 512) {
            float4 f = s[i]; int k = i >> 5, n = (i & 31) * 4;
            int k8 = k >> 3, kc = k8 >> 2, q = k8 & 3, w = k & 7;
            int base = ((n >> 4) * 4 + kc) * 512 + (q * 16 + (n & 15)) * 8 + w;
            wB[base] = f2bf(f.x); wB[base + 8] = f2bf(f.y);
            wB[base + 16] = f2bf(f.z); wB[base + 24] = f2bf(f.w);
        }
    }
    if (flags[2]) {
        const ushort4* s = (const ushort4*)W1r;
        for (int i = tid; i < 2048; i += 512) {
            ushort4 v = s[i]; int k = i >> 5, n = (i & 31) * 4;
            int k8g = 8 + (k >> 3), kc = k8g >> 2, q = k8g & 3, w = k & 7;
            int base = ((n >> 4) * 4 + kc) * 512 + (q * 16 + (n & 15)) * 8 + w;
            wB[base] = v.x; wB[base + 8] = v.y; wB[base + 16] = v.z; wB[base + 24] = v.w;
        }
    } else {
        const float4* s = (const float4*)W1r;
        for (int i = tid; i < 2048; i += 512) {
            float4 f = s[i]; int k = i >> 5, n = (i & 31) * 4;
            int k8g = 8 + (k >> 3), kc = k8g >> 2, q = k8g & 3, w = k & 7;
            int base = ((n >> 4) * 4 + kc) * 512 + (q * 16 + (n & 15)) * 8 + w;
            wB[base] = f2bf(f.x); wB[base + 8] = f2bf(f.y);
            wB[base + 16] = f2bf(f.z); wB[base + 24] = f2bf(f.w);
        }
    }
    if (tid < 128) b_s[tid] = flags[3] ? bf2f(((const u16*)b1)[tid]) : ((const float*)b1)[tid];

    int grp = tid >> 4, gl = tid & 15;
    int n = node0 + grp;
    int mtile = grp >> 4, l15m = grp & 15;
    int idx_mean = (mtile * 4 + (gl >> 3)) * 512 + (((gl >> 1) & 3) * 16 + l15m) * 8 + (gl & 1) * 4;
    int idx_x = (mtile * 4 + 2 + (gl >> 3)) * 512 + (((gl >> 1) & 3) * 16 + l15m) * 8 + (gl & 1) * 4;
    if (n < nn) {
        int beg = off[n], deg = cnt[n];
        float a0 = 0.f, a1 = 0.f, a2 = 0.f, a3 = 0.f;
        int i = 0;
        if (xbf) {
            const u16* xb = (const u16*)x + gl * 4;
            for (; i + 8 <= deg; i += 8) {
                ushort4 v[8];
#pragma unroll
                for (int j = 0; j < 8; j++) {
                    int s0 = esrc[beg + i + j];
                    v[j] = *(const ushort4*)(xb + (size_t)s0 * 64);
                }
#pragma unroll
                for (int j = 0; j < 8; j++) {
                    a0 += bf2f(v[j].x); a1 += bf2f(v[j].y);
                    a2 += bf2f(v[j].z); a3 += bf2f(v[j].w);
                }
            }
            for (; i < deg; i++) {
                int s0 = esrc[beg + i];
                ushort4 v = *(const ushort4*)(xb + (size_t)s0 * 64);
                a0 += bf2f(v.x); a1 += bf2f(v.y); a2 += bf2f(v.z); a3 += bf2f(v.w);
            }
        } else {
            const float* xb = (const float*)x + gl * 4;
            for (; i + 8 <= deg; i += 8) {
                float4 v[8];
#pragma unroll
                for (int j = 0; j < 8; j++) {
                    int s0 = esrc[beg + i + j];
                    v[j] = *(const float4*)(xb + (size_t)s0 * 64);
                }
#pragma unroll
                for (int j = 0; j < 8; j++) {
                    a0 += v[j].x; a1 += v[j].y; a2 += v[j].z; a3 += v[j].w;
                }
            }
            for (; i < deg; i++) {
                int s0 = esrc[beg + i];
                float4 v = *(const float4*)(xb + (size_t)s0 * 64);
                a0 += v.x; a1 += v.y; a2 += v.z; a3 += v.w;
            }
        }
        float inv = 1.0f / (float)(deg > 0 ? deg : 1);
        *(ushort4*)&wA[idx_mean] =
            make_ushort4(f2bf(a0 * inv), f2bf(a1 * inv), f2bf(a2 * inv), f2bf(a3 * inv));
        if (xbf) {
            *(ushort4*)&wA[idx_x] =
                *(const ushort4*)((const u16*)x + (size_t)n * 64 + gl * 4);
        } else {
            float4 xv = *(const float4*)((const float*)x + (size_t)n * 64 + gl * 4);
            *(ushort4*)&wA[idx_x] =
                make_ushort4(f2bf(xv.x), f2bf(xv.y), f2bf(xv.z), f2bf(xv.w));
        }
    } else {
        *(ushort4*)&wA[idx_mean] = make_ushort4(0, 0, 0, 0);
        *(ushort4*)&wA[idx_x] = make_ushort4(0, 0, 0, 0);
    }
    __syncthreads();

    int wv = tid >> 6, lane = tid & 63;
    int l15 = lane & 15, q = lane >> 4;
    f32x4 acc0 = {0.f, 0.f, 0.f, 0.f};
    f32x4 acc1 = {0.f, 0.f, 0.f, 0.f};
#pragma unroll
    for (int kc = 0; kc < 4; kc++) {
        short8 a0 = *(const short8*)&wA[(kc) * 512 + lane * 8];
        short8 a1 = *(const short8*)&wA[(4 + kc) * 512 + lane * 8];
        short8 b  = *(const short8*)&wB[(wv * 4 + kc) * 512 + lane * 8];
        acc0 = __builtin_amdgcn_mfma_f32_16x16x32_bf16(a0, b, acc0, 0, 0, 0);
        acc1 = __builtin_amdgcn_mfma_f32_16x16x32_bf16(a1, b, acc1, 0, 0, 0);
    }
    int nc = wv * 16 + l15;
    float bias = b_s[nc];
#pragma unroll
    for (int r = 0; r < 4; r++) {
        int m = q * 4 + r;
        int nd = node0 + m;
        if (nd < nn) h[(size_t)nd * 128 + nc] = f2bf(fmaxf(acc0[r] + bias, 0.0f));
        nd = node0 + 16 + m;
        if (nd < nn) h[(size_t)nd * 128 + nc] = f2bf(fmaxf(acc1[r] + bias, 0.0f));
    }
}

// ---------------- layer 2 (R8 structure) ----------------
// Tile M=32,N=64,K=256. Fragment-major LDS; chunk(tile,kc)=1KB.
__global__ __launch_bounds__(512, 4) void layer2(
    const u16* __restrict__ h, const int* __restrict__ esrc,
    const int* __restrict__ off, const int* __restrict__ cnt,
    const void* __restrict__ W2l, const void* __restrict__ W2r,
    const void* __restrict__ b2, void* __restrict__ out,
    const int* __restrict__ flags, int nn) {
    __shared__ __align__(16) u16 wB2[32 * 512];  // 32 KB, (ntile*8+kc)
    __shared__ __align__(16) u16 wA2[16 * 512];  // 16 KB, (mtile*8+kc)
    __shared__ float b_s[64];
    int tid = threadIdx.x;
    int node0 = blockIdx.x * 32;
    int obf = flags[0];

    if (flags[4]) {
        const ushort4* s = (const ushort4*)W2l;
        for (int i = tid; i < 2048; i += 512) {
            ushort4 v = s[i]; int k = i >> 4, n = (i & 15) * 4;
            int k8 = k >> 3, kc = k8 >> 2, q = k8 & 3, w = k & 7;
            int base = ((n >> 4) * 8 + kc) * 512 + (q * 16 + (n & 15)) * 8 + w;
            wB2[base] = v.x; wB2[base + 8] = v.y; wB2[base + 16] = v.z; wB2[base + 24] = v.w;
        }
    } else {
        const float4* s = (const float4*)W2l;
        for (int i = tid; i < 2048; i += 512) {
            float4 f = s[i]; int k = i >> 4, n = (i & 15) * 4;
            int k8 = k >> 3, kc = k8 >> 2, q = k8 & 3, w = k & 7;
            int base = ((n >> 4) * 8 + kc) * 512 + (q * 16 + (n & 15)) * 8 + w;
            wB2[base] = f2bf(f.x); wB2[base + 8] = f2bf(f.y);
            wB2[base + 16] = f2bf(f.z); wB2[base + 24] = f2bf(f.w);
        }
    }
    if (flags[5]) {
        const ushort4* s = (const ushort4*)W2r;
        for (int i = tid; i < 2048; i += 512) {
            ushort4 v = s[i]; int k = i >> 4, n = (i & 15) * 4;
            int k8g = 16 + (k >> 3), kc = k8g >> 2, q = k8g & 3, w = k & 7;
            int base = ((n >> 4) * 8 + kc) * 512 + (q * 16 + (n & 15)) * 8 + w;
            wB2[base] = v.x; wB2[base + 8] = v.y; wB2[base + 16] = v.z; wB2[base + 24] = v.w;
        }
    } else {
        const float4* s = (const float4*)W2r;
        for (int i = tid; i < 2048; i += 512) {
            float4 f = s[i]; int k = i >> 4, n = (i & 15) * 4;
            int k8g = 16 + (k >> 3), kc = k8g >> 2, q = k8g & 3, w = k & 7;
            int base = ((n >> 4) * 8 + kc) * 512 + (q * 16 + (n & 15)) * 8 + w;
            wB2[base] = f2bf(f.x); wB2[base + 8] = f2bf(f.y);
            wB2[base + 16] = f2bf(f.z); wB2[base + 24] = f2bf(f.w);
        }
    }
    if (tid < 64) b_s[tid] = flags[6] ? bf2f(((const u16*)b2)[tid]) : ((const float*)b2)[tid];

    int grp = tid >> 4, gl = tid & 15;
    int n = node0 + grp;
    int mtile = grp >> 4, l15m = grp & 15;
    int idx_mean = (mtile * 8 + (gl >> 2)) * 512 + ((gl & 3) * 16 + l15m) * 8;
    int idx_h = (mtile * 8 + 4 + (gl >> 2)) * 512 + ((gl & 3) * 16 + l15m) * 8;
    if (n < nn) {
        int beg = off[n], deg = cnt[n];
        float a[8];
#pragma unroll
        for (int j = 0; j < 8; j++) a[j] = 0.0f;
        const u16* hb = h + (size_t)gl * 8;
        int i = 0;
        for (; i + 8 <= deg; i += 8) {
            uint4 v[8];
#pragma unroll
            for (int j = 0; j < 8; j++) {
                int s0 = esrc[beg + i + j];
                v[j] = *(const uint4*)(hb + (size_t)s0 * 128);
            }
#pragma unroll
            for (int j = 0; j < 8; j++) {
                a[0] += bfu_lo(v[j].x); a[1] += bfu_hi(v[j].x);
                a[2] += bfu_lo(v[j].y); a[3] += bfu_hi(v[j].y);
                a[4] += bfu_lo(v[j].z); a[5] += bfu_hi(v[j].z);
                a[6] += bfu_lo(v[j].w); a[7] += bfu_hi(v[j].w);
            }
        }
        for (; i < deg; i++) {
            int s0 = esrc[beg + i];
            uint4 v = *(const uint4*)(hb + (size_t)s0 * 128);
            a[0] += bfu_lo(v.x); a[1] += bfu_hi(v.x);
            a[2] += bfu_lo(v.y); a[3] += bfu_hi(v.y);
            a[4] += bfu_lo(v.z); a[5] += bfu_hi(v.z);
            a[6] += bfu_lo(v.w); a[7] += bfu_hi(v.w);
        }
        float inv = 1.0f / (float)(deg > 0 ? deg : 1);
        *(ushort4*)&wA2[idx_mean] =
            make_ushort4(f2bf(a[0] * inv), f2bf(a[1] * inv), f2bf(a[2] * inv), f2bf(a[3] * inv));
        *(ushort4*)&wA2[idx_mean + 4] =
            make_ushort4(f2bf(a[4] * inv), f2bf(a[5] * inv), f2bf(a[6] * inv), f2bf(a[7] * inv));
        uint4 hv = *(const uint4*)(h + (size_t)n * 128 + gl * 8);
        *(uint4*)&wA2[idx_h] = hv;
    } else {
        *(ushort4*)&wA2[idx_mean] = make_ushort4(0, 0, 0, 0);
        *(ushort4*)&wA2[idx_mean + 4] = make_ushort4(0, 0, 0, 0);
        *(uint4*)&wA2[idx_h] = make_uint4(0, 0, 0, 0);
    }
    __syncthreads();

    int wv = tid >> 6, lane = tid & 63;
    int l15 = lane & 15, q = lane >> 4;
    int mt = wv >> 2, nt = wv & 3;
    f32x4 acc = {0.f, 0.f, 0.f, 0.f};
#pragma unroll
    for (int kc = 0; kc < 8; kc++) {
        short8 a = *(const short8*)&wA2[(mt * 8 + kc) * 512 + lane * 8];
        short8 b = *(const short8*)&wB2[(nt * 8 + kc) * 512 + lane * 8];
        acc = __builtin_amdgcn_mfma_f32_16x16x32_bf16(a, b, acc, 0, 0, 0);
    }
    int nc = nt * 16 + l15;
    float bias = b_s[nc];
#pragma unroll
    for (int r = 0; r < 4; r++) {
        int m = q * 4 + r;
        int nd = node0 + mt * 16 + m;
        if (nd < nn) {
            float v = acc[r] + bias;
            if (obf) ((u16*)out)[(size_t)nd * 64 + nc] = f2bf(v);
            else     ((float*)out)[(size_t)nd * 64 + nc] = v;
        }
    }
}

// ---------------- fallback ----------------
__global__ __launch_bounds__(256) void zero_out_k(u16* __restrict__ out, int n) {
    int i = blockIdx.x * 256 + threadIdx.x;
    if (i < n) out[i] = 0;
}

extern "C" void kernel_launch(void* const* d_in, const int* in_sizes, int n_in,
                              void* d_out, int out_size, void* d_ws, size_t ws_size,
                              hipStream_t stream) {
    const void* x   = d_in[0];
    const void* ei  = d_in[1];
    const void* W1l = d_in[2];
    const void* W1r = d_in[3];
    const void* b1  = d_in[4];
    const void* W2l = d_in[5];
    const void* W2r = d_in[6];
    const void* b2  = d_in[7];

    int nn = in_sizes[0] / 64;
    int ne = in_sizes[1] / 2;
    int nb = (nn + BSIZE - 1) / BSIZE;
    int nchunk = (ne + CHUNK - 1) / CHUNK;

    auto al = [](size_t v) { return (v + 255) & ~(size_t)255; };
    size_t o_flags = 0;
    size_t o_bo    = 256;                              // (nb+1) ints
    size_t o_btot  = al(o_bo + 513 * 4);               // 512 ints
    size_t o_cnt   = al(o_btot + 512 * 4);
    size_t o_off   = al(o_cnt + (size_t)nn * 4);
    size_t o_esrc  = al(o_off + (size_t)nn * 4);
    size_t o_h     = al(o_esrc + (size_t)ne * 4);
    size_t ws_req  = o_h + (size_t)nn * 128 * 2;

    // overlays inside the h region (all dead before layer1 writes h):
    size_t o_ep   = o_h;                               // ne*4 B
    size_t o_h2d  = al(o_ep + (size_t)ne * 4);         // nb*NCP*4
    size_t o_b2d  = al(o_h2d + (size_t)512 * NCP * 4); // nb*NCP*4
    size_t ov_end = o_b2d + (size_t)512 * NCP * 4;

    bool ok = ws_size >= ws_req && nb >= 1 && nb <= 512 && nn <= 131072 &&
              nchunk <= NCP && ov_end <= ws_req;
    if (!ok) {
        zero_out_k<<<(out_size + 255) / 256, 256, 0, stream>>>((u16*)d_out, out_size);
        return;
    }

    char* ws = (char*)d_ws;
    int* flags  = (int*)(ws + o_flags);
    int* bo     = (int*)(ws + o_bo);
    int* btot   = (int*)(ws + o_btot);
    int* cnt    = (int*)(ws + o_cnt);
    int* off    = (int*)(ws + o_off);
    int* esrc   = (int*)(ws + o_esrc);
    u16* h      = (u16*)(ws + o_h);
    unsigned* ep = (unsigned*)(ws + o_ep);
    int* hist2d = (int*)(ws + o_h2d);
    int* base2d = (int*)(ws + o_b2d);

    probe_k<<<1, 256, 0, stream>>>(x, W1l, W1r, b1, W2l, W2r, b2, ei, flags, ne,
                                   in_sizes[0], in_sizes[2], in_sizes[3], in_sizes[4],
                                   in_sizes[5], in_sizes[6], in_sizes[7]);
    count_chunks<<<nchunk, 512, 0, stream>>>(ei, hist2d, flags, nn, ne, nb);
    scan2d<<<nb, 256, 0, stream>>>(hist2d, base2d, btot, nchunk);
    scan_buckets<<<1, 512, 0, stream>>>(btot, bo, nb);
    partition_k<<<nchunk, 512, 0, stream>>>(ei, bo, base2d, ep, flags, nn, ne, nb);
    csr_fill2<<<nb, 512, 0, stream>>>(ep, bo, off, cnt, esrc, nn);
    int lb = (nn + 31) / 32;
    layer1<<<lb, 512, 0, stream>>>(x, esrc, off, cnt, W1l, W1r, b1, h, flags, nn);
    layer2<<<lb, 512, 0, stream>>>(h, esrc, off, cnt, W2l, W2r, b2, d_out, flags, nn);
}